// Round 5
// baseline (506.127 us; speedup 1.0000x reference)
//
#include <hip/hip_runtime.h>

#define N_NODES 100000
#define N_EDGES 1600000
#define F_IN    512
#define HIDDEN  16
#define N_CLS   40

#define BSHIFT  7
#define BSIZE   128                                // nodes per bucket
#define NB      ((N_NODES + BSIZE - 1) / BSIZE)    // 782 buckets
#define NWGBIN  256
#define CHUNK   (N_EDGES / NWGBIN)                 // 6250 (exact)
#define CSR_CAP (N_EDGES + NB * 512 + 64)          // padded csr capacity

static_assert(N_EDGES % NWGBIN == 0, "chunking must be exact");

// ---------------- zero bucket counters + sentinel pad rows ----------------
__global__ void k_zero(int* __restrict__ bucketCnt,
                       float* __restrict__ h1pad, float* __restrict__ gpad) {
    int i = blockIdx.x * blockDim.x + threadIdx.x;
    if (i < NB) bucketCnt[i] = 0;
    if (i < HIDDEN) { h1pad[i] = 0.0f; gpad[i] = 0.0f; }
}

// ---------------- pass A: per-bucket edge counts ----------------
__global__ __launch_bounds__(256) void k_binc(const int* __restrict__ ei,
                                              int* __restrict__ bucketCnt) {
    __shared__ int h[NB];
    int t = threadIdx.x;
    for (int b = t; b < NB; b += 256) h[b] = 0;
    __syncthreads();
    int start = blockIdx.x * CHUNK, end = start + CHUNK;
    for (int e = start + t; e < end; e += 256)
        atomicAdd(&h[ei[N_EDGES + e] >> BSHIFT], 1);
    __syncthreads();
    for (int b = t; b < NB; b += 256)
        if (h[b]) atomicAdd(&bucketCnt[b], h[b]);
}

// ---------------- exclusive scan of 782 bucket counts ----------------
__global__ __launch_bounds__(1024) void k_bscan(const int* __restrict__ bucketCnt,
                                                int* __restrict__ boff,
                                                int* __restrict__ cur) {
    __shared__ int s[1024];
    int t = threadIdx.x;
    int v = (t < NB) ? bucketCnt[t] : 0;
    s[t] = v; __syncthreads();
    for (int o = 1; o < 1024; o <<= 1) {
        int add = (t >= o) ? s[t - o] : 0;
        __syncthreads();
        s[t] += add;
        __syncthreads();
    }
    if (t < NB) { int ex = s[t] - v; boff[t] = ex; cur[t] = ex; }
    if (t == 0) boff[NB] = N_EDGES;
}

// ---------------- pass B: place packed edges (r | lc<<17) ----------------
__global__ __launch_bounds__(256) void k_bfill(const int* __restrict__ ei,
                                               int* __restrict__ cur,
                                               int* __restrict__ binned) {
    __shared__ int lc[NB];
    int t = threadIdx.x;
    int start = blockIdx.x * CHUNK, end = start + CHUNK;
    for (int b = t; b < NB; b += 256) lc[b] = 0;
    __syncthreads();
    for (int e = start + t; e < end; e += 256)
        atomicAdd(&lc[ei[N_EDGES + e] >> BSHIFT], 1);
    __syncthreads();
    for (int b = t; b < NB; b += 256) {
        int c = lc[b];
        lc[b] = c ? atomicAdd(&cur[b], c) : 0;
    }
    __syncthreads();
    for (int e = start + t; e < end; e += 256) {
        int r = ei[e], c = ei[N_EDGES + e];
        int b = c >> BSHIFT;
        int pos = atomicAdd(&lc[b], 1);
        binned[pos] = r | ((c & (BSIZE - 1)) << 17);
    }
}

// ------ per-bucket counting sort -> 4-aligned padded CSR + offsets/cnt/dis ----
// Node segments padded to multiple of 4 with sentinel N_NODES (zero feature row).
__global__ __launch_bounds__(256) void k_csr(const int* __restrict__ boff,
                                             const int* __restrict__ binned,
                                             int* __restrict__ csr,
                                             int* __restrict__ offsets,
                                             int* __restrict__ cnt,
                                             float* __restrict__ dis) {
    __shared__ int h[BSIZE];
    __shared__ int sc[BSIZE];
    __shared__ int curL[BSIZE];
    int t = threadIdx.x, b = blockIdx.x;
    if (t < BSIZE) h[t] = 0;
    __syncthreads();
    int s = boff[b], e = boff[b + 1];
    for (int i = s + t; i < e; i += 256)
        atomicAdd(&h[binned[i] >> 17], 1);
    __syncthreads();
    int v  = (t < BSIZE) ? h[t] : 0;
    int vp = (v + 3) & ~3;                // padded count
    if (t < BSIZE) sc[t] = vp;
    __syncthreads();
    for (int o = 1; o < BSIZE; o <<= 1) {
        int add = (t < BSIZE && t >= o) ? sc[t - o] : 0;
        __syncthreads();
        if (t < BSIZE) sc[t] += add;
        __syncthreads();
    }
    int base = ((s + 3) & ~3) + b * 512;  // 4-aligned bucket base, 512 slack/bucket
    if (t < BSIZE) {
        int ex = base + sc[t] - vp;       // 4-aligned node start
        curL[t] = ex;
        int node = b * BSIZE + t;
        if (node < N_NODES) {
            offsets[node] = ex;
            cnt[node]     = v;
            dis[node]     = rsqrtf(1.0f + (float)v);
        }
        for (int j = v; j < vp; ++j) csr[ex + j] = N_NODES;   // sentinel pads
    }
    __syncthreads();
    for (int i = s + t; i < e; i += 256) {
        int p = binned[i];
        int pos = atomicAdd(&curL[p >> 17], 1);
        csr[pos] = p & 0x1FFFF;
    }
}

// ---------------- layer-1 GEMM: h1s = (x @ W1) * dis ----------------
// 4 lanes/row, 2 rows/thread (stride 64), 128 rows per 256-thread WG.
// sW stride 17: the 4 quad addresses span 16 distinct banks -> conflict-free.
__global__ __launch_bounds__(256) void k_gemm1(
        const float* __restrict__ x, const float* __restrict__ W1,
        const float* __restrict__ dis, float* __restrict__ h1s) {
    __shared__ float sW[F_IN * 17];   // 34816 B -> 4 blocks/CU
    for (int idx = threadIdx.x; idx < F_IN * HIDDEN; idx += 256) {
        int k = idx >> 4, j = idx & 15;
        sW[k * 17 + j] = W1[idx];
    }
    __syncthreads();

    int t = threadIdx.x;
    int q = t & 3;
    int row0 = blockIdx.x * 128 + (t >> 2);
    int row1 = row0 + 64;
    bool ok0 = row0 < N_NODES, ok1 = row1 < N_NODES;
    // clamp for loads (no per-load cndmask); guard only the stores
    int r0c = ok0 ? row0 : (N_NODES - 1);
    int r1c = ok1 ? row1 : (N_NODES - 1);
    const float* x0 = x + (size_t)r0c * F_IN;
    const float* x1 = x + (size_t)r1c * F_IN;

    float acc[2][16];
#pragma unroll
    for (int rr = 0; rr < 2; ++rr)
#pragma unroll
        for (int j = 0; j < 16; ++j) acc[rr][j] = 0.0f;

#pragma unroll 4
    for (int i = 0; i < 32; ++i) {
        int k0 = i * 16 + q * 4;
        float4 xv0 = *(const float4*)(x0 + k0);
        float4 xv1 = *(const float4*)(x1 + k0);
#pragma unroll
        for (int kk = 0; kk < 4; ++kk) {
            const float* wr = &sW[(k0 + kk) * 17];
            float4 w0 = *(const float4*)(wr);
            float4 w1 = *(const float4*)(wr + 4);
            float4 w2 = *(const float4*)(wr + 8);
            float4 w3 = *(const float4*)(wr + 12);
            float xs0 = (&xv0.x)[kk], xs1 = (&xv1.x)[kk];
            acc[0][0]  = fmaf(xs0, w0.x, acc[0][0]);   acc[1][0]  = fmaf(xs1, w0.x, acc[1][0]);
            acc[0][1]  = fmaf(xs0, w0.y, acc[0][1]);   acc[1][1]  = fmaf(xs1, w0.y, acc[1][1]);
            acc[0][2]  = fmaf(xs0, w0.z, acc[0][2]);   acc[1][2]  = fmaf(xs1, w0.z, acc[1][2]);
            acc[0][3]  = fmaf(xs0, w0.w, acc[0][3]);   acc[1][3]  = fmaf(xs1, w0.w, acc[1][3]);
            acc[0][4]  = fmaf(xs0, w1.x, acc[0][4]);   acc[1][4]  = fmaf(xs1, w1.x, acc[1][4]);
            acc[0][5]  = fmaf(xs0, w1.y, acc[0][5]);   acc[1][5]  = fmaf(xs1, w1.y, acc[1][5]);
            acc[0][6]  = fmaf(xs0, w1.z, acc[0][6]);   acc[1][6]  = fmaf(xs1, w1.z, acc[1][6]);
            acc[0][7]  = fmaf(xs0, w1.w, acc[0][7]);   acc[1][7]  = fmaf(xs1, w1.w, acc[1][7]);
            acc[0][8]  = fmaf(xs0, w2.x, acc[0][8]);   acc[1][8]  = fmaf(xs1, w2.x, acc[1][8]);
            acc[0][9]  = fmaf(xs0, w2.y, acc[0][9]);   acc[1][9]  = fmaf(xs1, w2.y, acc[1][9]);
            acc[0][10] = fmaf(xs0, w2.z, acc[0][10]);  acc[1][10] = fmaf(xs1, w2.z, acc[1][10]);
            acc[0][11] = fmaf(xs0, w2.w, acc[0][11]);  acc[1][11] = fmaf(xs1, w2.w, acc[1][11]);
            acc[0][12] = fmaf(xs0, w3.x, acc[0][12]);  acc[1][12] = fmaf(xs1, w3.x, acc[1][12]);
            acc[0][13] = fmaf(xs0, w3.y, acc[0][13]);  acc[1][13] = fmaf(xs1, w3.y, acc[1][13]);
            acc[0][14] = fmaf(xs0, w3.z, acc[0][14]);  acc[1][14] = fmaf(xs1, w3.z, acc[1][14]);
            acc[0][15] = fmaf(xs0, w3.w, acc[0][15]);  acc[1][15] = fmaf(xs1, w3.w, acc[1][15]);
        }
    }

    // reduce-scatter over the 4 lanes: lane q ends holding j in [4q, 4q+4)
#pragma unroll
    for (int rr = 0; rr < 2; ++rr) {
        float t16[16];
#pragma unroll
        for (int j = 0; j < 16; ++j)
            t16[j] = acc[rr][j] + __shfl_xor(acc[rr][j], 2);
        float k8[8];
#pragma unroll
        for (int j = 0; j < 8; ++j)
            k8[j] = (q & 2) ? t16[8 + j] : t16[j];
        float t8[8];
#pragma unroll
        for (int j = 0; j < 8; ++j)
            t8[j] = k8[j] + __shfl_xor(k8[j], 1);
#pragma unroll
        for (int j = 0; j < 4; ++j)
            acc[rr][j] = (q & 1) ? t8[4 + j] : t8[j];
    }

    if (ok0) {
        float d = dis[row0];
        *(float4*)(h1s + (size_t)row0 * HIDDEN + q * 4) =
            { acc[0][0] * d, acc[0][1] * d, acc[0][2] * d, acc[0][3] * d };
    }
    if (ok1) {
        float d = dis[row1];
        *(float4*)(h1s + (size_t)row1 * HIDDEN + q * 4) =
            { acc[1][0] * d, acc[1][1] * d, acc[1][2] * d, acc[1][3] * d };
    }
}

// ---- agg layer 1: g = relu(dis*(self+Σ h1s[r]) + b1) * dis ----
// 4 lanes/node; one broadcast int4 csr load per 4 edges; 8 gathers in flight.
__global__ __launch_bounds__(256) void k_agg1(
        const int* __restrict__ offsets, const int* __restrict__ cnt,
        const int* __restrict__ csr, const float* __restrict__ dis,
        const float* __restrict__ b1,
        const float* __restrict__ h1s, float* __restrict__ g) {
    int t = blockIdx.x * 256 + threadIdx.x;
    int node = t >> 2;
    if (node >= N_NODES) return;
    int q = t & 3;

    float4 acc = *(const float4*)(h1s + (size_t)node * HIDDEN + q * 4);  // self
    const int4* cp = (const int4*)(csr + offsets[node]);   // 4-aligned
    int n4 = (cnt[node] + 3) >> 2;
    int i = 0;
    for (; i + 2 <= n4; i += 2) {
        int4 c0 = cp[i], c1 = cp[i + 1];
        float4 v0 = *(const float4*)(h1s + (size_t)c0.x * HIDDEN + q * 4);
        float4 v1 = *(const float4*)(h1s + (size_t)c0.y * HIDDEN + q * 4);
        float4 v2 = *(const float4*)(h1s + (size_t)c0.z * HIDDEN + q * 4);
        float4 v3 = *(const float4*)(h1s + (size_t)c0.w * HIDDEN + q * 4);
        float4 v4 = *(const float4*)(h1s + (size_t)c1.x * HIDDEN + q * 4);
        float4 v5 = *(const float4*)(h1s + (size_t)c1.y * HIDDEN + q * 4);
        float4 v6 = *(const float4*)(h1s + (size_t)c1.z * HIDDEN + q * 4);
        float4 v7 = *(const float4*)(h1s + (size_t)c1.w * HIDDEN + q * 4);
        acc.x += v0.x + v1.x + v2.x + v3.x + v4.x + v5.x + v6.x + v7.x;
        acc.y += v0.y + v1.y + v2.y + v3.y + v4.y + v5.y + v6.y + v7.y;
        acc.z += v0.z + v1.z + v2.z + v3.z + v4.z + v5.z + v6.z + v7.z;
        acc.w += v0.w + v1.w + v2.w + v3.w + v4.w + v5.w + v6.w + v7.w;
    }
    if (i < n4) {
        int4 c0 = cp[i];
        float4 v0 = *(const float4*)(h1s + (size_t)c0.x * HIDDEN + q * 4);
        float4 v1 = *(const float4*)(h1s + (size_t)c0.y * HIDDEN + q * 4);
        float4 v2 = *(const float4*)(h1s + (size_t)c0.z * HIDDEN + q * 4);
        float4 v3 = *(const float4*)(h1s + (size_t)c0.w * HIDDEN + q * 4);
        acc.x += v0.x + v1.x + v2.x + v3.x;
        acc.y += v0.y + v1.y + v2.y + v3.y;
        acc.z += v0.z + v1.z + v2.z + v3.z;
        acc.w += v0.w + v1.w + v2.w + v3.w;
    }
    float d = dis[node];
    float4 bq = *(const float4*)(b1 + q * 4);
    float4 r;
    r.x = fmaxf(fmaf(acc.x, d, bq.x), 0.0f) * d;
    r.y = fmaxf(fmaf(acc.y, d, bq.y), 0.0f) * d;
    r.z = fmaxf(fmaf(acc.z, d, bq.z), 0.0f) * d;
    r.w = fmaxf(fmaf(acc.w, d, bq.w), 0.0f) * d;
    *(float4*)(g + (size_t)node * HIDDEN + q * 4) = r;
}

// ---- agg layer 2: out = b2 + (dis*(self+Σ g[r])) @ W2 ----
__global__ __launch_bounds__(256) void k_agg2(
        const int* __restrict__ offsets, const int* __restrict__ cnt,
        const int* __restrict__ csr, const float* __restrict__ dis,
        const float* __restrict__ W2, const float* __restrict__ b2,
        const float* __restrict__ g, float* __restrict__ out) {
    __shared__ float sW[HIDDEN * N_CLS];
    __shared__ float sb2[N_CLS];
    __shared__ float sAgg[64][HIDDEN + 1];
    int t = threadIdx.x;
    for (int i = t; i < HIDDEN * N_CLS; i += 256) sW[i] = W2[i];
    if (t < N_CLS) sb2[t] = b2[t];

    int gt = blockIdx.x * 256 + t;
    int node = gt >> 2;
    int q = t & 3;
    int ln = t >> 2;

    if (node < N_NODES) {
        float4 acc = *(const float4*)(g + (size_t)node * HIDDEN + q * 4);  // self
        const int4* cp = (const int4*)(csr + offsets[node]);
        int n4 = (cnt[node] + 3) >> 2;
        int i = 0;
        for (; i + 2 <= n4; i += 2) {
            int4 c0 = cp[i], c1 = cp[i + 1];
            float4 v0 = *(const float4*)(g + (size_t)c0.x * HIDDEN + q * 4);
            float4 v1 = *(const float4*)(g + (size_t)c0.y * HIDDEN + q * 4);
            float4 v2 = *(const float4*)(g + (size_t)c0.z * HIDDEN + q * 4);
            float4 v3 = *(const float4*)(g + (size_t)c0.w * HIDDEN + q * 4);
            float4 v4 = *(const float4*)(g + (size_t)c1.x * HIDDEN + q * 4);
            float4 v5 = *(const float4*)(g + (size_t)c1.y * HIDDEN + q * 4);
            float4 v6 = *(const float4*)(g + (size_t)c1.z * HIDDEN + q * 4);
            float4 v7 = *(const float4*)(g + (size_t)c1.w * HIDDEN + q * 4);
            acc.x += v0.x + v1.x + v2.x + v3.x + v4.x + v5.x + v6.x + v7.x;
            acc.y += v0.y + v1.y + v2.y + v3.y + v4.y + v5.y + v6.y + v7.y;
            acc.z += v0.z + v1.z + v2.z + v3.z + v4.z + v5.z + v6.z + v7.z;
            acc.w += v0.w + v1.w + v2.w + v3.w + v4.w + v5.w + v6.w + v7.w;
        }
        if (i < n4) {
            int4 c0 = cp[i];
            float4 v0 = *(const float4*)(g + (size_t)c0.x * HIDDEN + q * 4);
            float4 v1 = *(const float4*)(g + (size_t)c0.y * HIDDEN + q * 4);
            float4 v2 = *(const float4*)(g + (size_t)c0.z * HIDDEN + q * 4);
            float4 v3 = *(const float4*)(g + (size_t)c0.w * HIDDEN + q * 4);
            acc.x += v0.x + v1.x + v2.x + v3.x;
            acc.y += v0.y + v1.y + v2.y + v3.y;
            acc.z += v0.z + v1.z + v2.z + v3.z;
            acc.w += v0.w + v1.w + v2.w + v3.w;
        }
        float d = dis[node];
        sAgg[ln][q*4+0] = acc.x * d;
        sAgg[ln][q*4+1] = acc.y * d;
        sAgg[ln][q*4+2] = acc.z * d;
        sAgg[ln][q*4+3] = acc.w * d;
    }
    __syncthreads();
    if (node >= N_NODES) return;

    float a[HIDDEN];
#pragma unroll
    for (int j = 0; j < HIDDEN; ++j) a[j] = sAgg[ln][j];

    int c0 = q * 10;
    float o[10];
#pragma unroll
    for (int k = 0; k < 10; ++k) o[k] = sb2[c0 + k];
#pragma unroll
    for (int j = 0; j < HIDDEN; ++j) {
        float aj = a[j];
        const float* wr = &sW[j * N_CLS + c0];
#pragma unroll
        for (int k = 0; k < 10; ++k) o[k] = fmaf(aj, wr[k], o[k]);
    }
    float* op = out + (size_t)node * N_CLS + c0;
#pragma unroll
    for (int k = 0; k < 10; ++k) op[k] = o[k];
}

extern "C" void kernel_launch(void* const* d_in, const int* in_sizes, int n_in,
                              void* d_out, int out_size, void* d_ws, size_t ws_size,
                              hipStream_t stream) {
    const float* x  = (const float*)d_in[0];
    const int*   ei = (const int*)d_in[1];
    const float* W1 = (const float*)d_in[2];
    const float* b1 = (const float*)d_in[3];
    const float* W2 = (const float*)d_in[4];
    const float* b2 = (const float*)d_in[5];
    float* out = (float*)d_out;

    // ws: bucketCnt | boff | cur | offsets | cnt | dis | binned | csr(padded) |
    //     h1s[(N+1)*16] | g[(N+1)*16]   ≈ 29 MB
    char* w = (char*)d_ws;
    int*   bucketCnt = (int*)w;    w += 1024 * 4;
    int*   boff      = (int*)w;    w += 1024 * 4;
    int*   cur       = (int*)w;    w += 1024 * 4;
    int*   offsets   = (int*)w;    w += (size_t)N_NODES * 4;
    int*   cnt       = (int*)w;    w += (size_t)N_NODES * 4;
    float* dis       = (float*)w;  w += (size_t)N_NODES * 4 + 64;
    int*   binned    = (int*)w;    w += (size_t)N_EDGES * 4;
    int*   csr       = (int*)w;    w += (size_t)CSR_CAP * 4;
    float* h1s       = (float*)w;  w += (size_t)(N_NODES + 1) * HIDDEN * 4;
    float* g         = (float*)w;

    const int gGemm = (N_NODES + 127) / 128;       // 782
    const int gAgg  = (N_NODES * 4 + 255) / 256;   // 1563

    k_zero <<<(NB + 255) / 256, 256, 0, stream>>>(bucketCnt,
                h1s + (size_t)N_NODES * HIDDEN, g + (size_t)N_NODES * HIDDEN);
    k_binc <<<NWGBIN, 256, 0, stream>>>(ei, bucketCnt);
    k_bscan<<<1, 1024, 0, stream>>>(bucketCnt, boff, cur);
    k_bfill<<<NWGBIN, 256, 0, stream>>>(ei, cur, binned);
    k_csr  <<<NB, 256, 0, stream>>>(boff, binned, csr, offsets, cnt, dis);
    k_gemm1<<<gGemm, 256, 0, stream>>>(x, W1, dis, h1s);
    k_agg1 <<<gAgg, 256, 0, stream>>>(offsets, cnt, csr, dis, b1, h1s, g);
    k_agg2 <<<gAgg, 256, 0, stream>>>(offsets, cnt, csr, dis, W2, b2, g, out);
}